// Round 10
// baseline (156.423 us; speedup 1.0000x reference)
//
#include <hip/hip_runtime.h>
#include <hip/hip_fp16.h>

constexpr int F  = 64;   // IN_FEATS == ATT_HEADS*H_FEATS
constexpr int HEADS = 4;
constexpr int CAP = 256;    // per-wave LDS slots in dst_gather
constexpr int CS_EPT = 8;   // edges per thread, count_sign
constexpr int PL_EPT = 4;   // edges per thread, place

// ---------------------------------------------------------------------------
// Pass 1 (per node), fp32 mirroring numpy BLAS (seq-k FMA from 0, bias after).
// Blocks [0,nb): W_d path (tfeat fp32, u/v f64) + zero cnt. Blocks [nb,2nb):
// W_w path (hp fp16, a_src/a_dst fp32). W transposed in LDS -> ds_read_b128.
// ---------------------------------------------------------------------------
__global__ __launch_bounds__(256) void node_kernel(
    const float* __restrict__ h,
    const float* __restrict__ W_w, const float* __restrict__ b_w,
    const float* __restrict__ W_a,
    const float* __restrict__ W_d, const float* __restrict__ b_d,
    const float* __restrict__ W_f,
    float* __restrict__ tfeat, __half* __restrict__ hp,
    double* __restrict__ u_arr, double* __restrict__ v_arr,
    float* __restrict__ a_src, float* __restrict__ a_dst,
    unsigned* __restrict__ cnt, int N, int nb)
{
    __shared__ float sWT[F * F];     // [j][k] transposed
    __shared__ float sb[F];
    __shared__ double swfA[F], swfB[F];
    __shared__ float sWa[32];

    int tid = threadIdx.x;
    bool isW = blockIdx.x >= nb;     // W_w path?
    const float* Wsrc = isW ? W_w : W_d;
    for (int i = tid; i < F * F; i += 256) {
        int k = i >> 6, j = i & 63;
        sWT[j * F + k] = Wsrc[i];
    }
    if (tid < F) sb[tid] = isW ? b_w[tid] : b_d[tid];
    if (!isW && tid < F) {
        swfA[tid] = (double)W_f[tid] + (double)W_f[2 * F + tid];
        swfB[tid] = (double)W_f[F + tid] - (double)W_f[2 * F + tid];
    }
    if (isW && tid < 32) sWa[tid] = W_a[tid];
    __syncthreads();

    int blk = isW ? (blockIdx.x - nb) : blockIdx.x;
    int n = blk * 256 + tid;
    if (n >= N) return;

    if (!isW) cnt[n] = 0;            // replaces the memset dispatch

    float4 hv[16];
    const float4* h4 = reinterpret_cast<const float4*>(h + (size_t)n * F);
#pragma unroll
    for (int i = 0; i < 16; i++) hv[i] = h4[i];

    if (!isW) {
        // ---- W_d path: tfeat row + u,v (f64, j-sequential) ----
        double u = 0.0, v = 0.0;
        float4 tq;
        float4* trow = reinterpret_cast<float4*>(tfeat + (size_t)n * F);
#pragma unroll 4
        for (int j = 0; j < F; j++) {
            const float4* row = reinterpret_cast<const float4*>(&sWT[j * F]);
            float t = 0.f;
#pragma unroll
            for (int kk = 0; kk < 16; kk++) {
                float4 w = row[kk];
                float4 x = hv[kk];
                t = fmaf(x.x, w.x, t);
                t = fmaf(x.y, w.y, t);
                t = fmaf(x.z, w.z, t);
                t = fmaf(x.w, w.w, t);
            }
            t = t + sb[j];
            u = fma((double)t, swfA[j], u);
            v = fma((double)t, swfB[j], v);
            if ((j & 3) == 0) tq.x = t;
            else if ((j & 3) == 1) tq.y = t;
            else if ((j & 3) == 2) tq.z = t;
            else { tq.w = t; trow[j >> 2] = tq; }
        }
        u_arr[n] = u;
        v_arr[n] = v;
    } else {
        // ---- W_w path: hp row (fp16) + a_src,a_dst per head ----
        __half2* prow = reinterpret_cast<__half2*>(hp + (size_t)n * F);
#pragma unroll
        for (int qh = 0; qh < 4; qh++) {
            float asq = 0.f, adq = 0.f;
            float pprev = 0.f;
#pragma unroll 4
            for (int jj = 0; jj < 16; jj++) {
                int j = qh * 16 + jj;
                const float4* row = reinterpret_cast<const float4*>(&sWT[j * F]);
                float p = 0.f;
#pragma unroll
                for (int kk = 0; kk < 16; kk++) {
                    float4 w = row[kk];
                    float4 x = hv[kk];
                    p = fmaf(x.x, w.x, p);
                    p = fmaf(x.y, w.y, p);
                    p = fmaf(x.z, w.z, p);
                    p = fmaf(x.w, w.w, p);
                }
                p = p + sb[j];
                asq = fmaf(p, sWa[jj], asq);
                adq = fmaf(p, sWa[16 + jj], adq);
                if ((jj & 1) == 0) pprev = p;
                else prow[j >> 1] = __floats2half2_rn(pprev, p);
            }
            a_src[n * HEADS + qh] = asq;
            a_dst[n * HEADS + qh] = adq;
        }
    }
}

// ---------------------------------------------------------------------------
// Tier-2 sign fallback: literal fp32 192-term sequential FMA in the
// reference's e_feat section order (rare: |f64 margin| < 1e-4).
// ---------------------------------------------------------------------------
__device__ __noinline__ float tier2_sign(
    const float* __restrict__ tfeat, const float* __restrict__ sWf,
    int s, int d, float bf)
{
    const float4* ts = reinterpret_cast<const float4*>(tfeat + (size_t)s * F);
    const float4* td = reinterpret_cast<const float4*>(tfeat + (size_t)d * F);
    float sv[F];
#pragma unroll
    for (int i = 0; i < 16; i++) {
        float4 a = ts[i];
        sv[4 * i + 0] = a.x; sv[4 * i + 1] = a.y;
        sv[4 * i + 2] = a.z; sv[4 * i + 3] = a.w;
    }
    float acc = 0.f;
#pragma unroll
    for (int j = 0; j < F; j++) acc = fmaf(sv[j], sWf[j], acc);
#pragma unroll
    for (int i = 0; i < 16; i++) {
        float4 a = td[i];
        acc = fmaf(a.x, sWf[F + 4 * i + 0], acc);
        acc = fmaf(a.y, sWf[F + 4 * i + 1], acc);
        acc = fmaf(a.z, sWf[F + 4 * i + 2], acc);
        acc = fmaf(a.w, sWf[F + 4 * i + 3], acc);
    }
#pragma unroll
    for (int i = 0; i < 16; i++) {
        float4 a = td[i];
        acc = fmaf(sv[4 * i + 0] - a.x, sWf[2 * F + 4 * i + 0], acc);
        acc = fmaf(sv[4 * i + 1] - a.y, sWf[2 * F + 4 * i + 1], acc);
        acc = fmaf(sv[4 * i + 2] - a.z, sWf[2 * F + 4 * i + 2], acc);
        acc = fmaf(sv[4 * i + 3] - a.w, sWf[2 * F + 4 * i + 3], acc);
    }
    float sp = acc + bf;
    return (sp > 0.f) ? 1.f : (sp < 0.f ? -1.f : 0.f);
}

// ---------------------------------------------------------------------------
// CSR step 1 + sign: 8 edges/thread, batched independent chains.
// Order: 8 idx loads -> 8 atomics -> 8 u/v gather pairs -> signs -> 8 stores.
// pc[e] = pos | code<<30 (coalesced by e).
// ---------------------------------------------------------------------------
__global__ __launch_bounds__(256) void count_sign_kernel(
    const int* __restrict__ src_idx, const int* __restrict__ dst_idx,
    const double* __restrict__ u_arr, const double* __restrict__ v_arr,
    const float* __restrict__ tfeat, const float* __restrict__ W_f,
    const float* __restrict__ b_f,
    unsigned* __restrict__ cnt, unsigned* __restrict__ pc, int E)
{
    __shared__ float sWf[3 * F];
    int tid = threadIdx.x;
    if (tid < 3 * F) sWf[tid] = W_f[tid];
    __syncthreads();

    float bf = b_f[0];
    int base = blockIdx.x * (256 * CS_EPT) + tid;

    int  s[CS_EPT], d[CS_EPT];
    bool ok[CS_EPT];
#pragma unroll
    for (int i = 0; i < CS_EPT; i++) {
        int e = base + i * 256;
        ok[i] = e < E;
        s[i] = ok[i] ? src_idx[e] : 0;
        d[i] = ok[i] ? dst_idx[e] : 0;
    }

    unsigned p[CS_EPT];
#pragma unroll
    for (int i = 0; i < CS_EPT; i++)
        p[i] = ok[i] ? atomicAdd(&cnt[d[i]], 1u) : 0u;

    double uu[CS_EPT], vv[CS_EPT];
#pragma unroll
    for (int i = 0; i < CS_EPT; i++) {
        uu[i] = ok[i] ? u_arr[s[i]] : 0.0;
        vv[i] = ok[i] ? v_arr[d[i]] : 0.0;
    }

#pragma unroll
    for (int i = 0; i < CS_EPT; i++) {
        if (!ok[i]) continue;
        double m = uu[i] + vv[i] + (double)bf;
        float sg = (fabs(m) >= 1e-4) ? ((m > 0.0) ? 1.f : -1.f)
                                     : tier2_sign(tfeat, sWf, s[i], d[i], bf);
        unsigned code = (sg > 0.f) ? 0u : (sg < 0.f ? 1u : 2u);
        pc[base + i * 256] = p[i] | (code << 30);
    }
}

// ---------------------------------------------------------------------------
// CSR scan: scan1 (per-256-chunk local scan + chunk totals), scan3 (per-block
// reduce of preceding chunk totals + add + rowptr[N]).
// ---------------------------------------------------------------------------
__global__ __launch_bounds__(256) void scan1_kernel(
    const unsigned* __restrict__ cnt, unsigned* __restrict__ rowptr,
    unsigned* __restrict__ bsum, int N)
{
    int t = threadIdx.x;
    int i = blockIdx.x * 256 + t;
    unsigned v = (i < N) ? cnt[i] : 0u;
    unsigned x = v;
#pragma unroll
    for (int off = 1; off < 64; off <<= 1) {
        unsigned y = __shfl_up(x, off);
        if ((t & 63) >= off) x += y;
    }
    __shared__ unsigned wsum[4];
    if ((t & 63) == 63) wsum[t >> 6] = x;
    __syncthreads();
    unsigned pre = 0;
#pragma unroll
    for (int w = 0; w < 3; w++) if (w < (t >> 6)) pre += wsum[w];
    unsigned incl = x + pre;
    if (i < N) rowptr[i] = incl - v;
    if (t == 255) bsum[blockIdx.x] = incl;
}

__global__ __launch_bounds__(256) void scan3_kernel(
    unsigned* __restrict__ rowptr, const unsigned* __restrict__ bsum,
    int N, int E, int nb)
{
    int t = threadIdx.x;
    int lim = min((int)blockIdx.x, nb);
    unsigned v = 0;
    for (int w = t; w < lim; w += 256) v += bsum[w];
#pragma unroll
    for (int off = 32; off >= 1; off >>= 1) v += __shfl_xor(v, off);
    __shared__ unsigned ws[4];
    if ((t & 63) == 0) ws[t >> 6] = v;
    __syncthreads();
    unsigned prefix = ws[0] + ws[1] + ws[2] + ws[3];

    int i = blockIdx.x * 256 + t;
    if (i < N) rowptr[i] += prefix;
    if (i == 0) rowptr[N] = (unsigned)E;
}

// ---------------------------------------------------------------------------
// CSR step 3: pure placement, 4 edges/thread, independent chains, no atomics.
// ---------------------------------------------------------------------------
__global__ __launch_bounds__(256) void place_kernel(
    const int* __restrict__ src_idx, const int* __restrict__ dst_idx,
    const unsigned* __restrict__ pc, const unsigned* __restrict__ rowptr,
    unsigned* __restrict__ src_packed, int E)
{
    int base = blockIdx.x * (256 * PL_EPT) + threadIdx.x;

    unsigned pv[PL_EPT];
    int dd[PL_EPT], ss[PL_EPT];
    bool ok[PL_EPT];
#pragma unroll
    for (int i = 0; i < PL_EPT; i++) {
        int e = base + i * 256;
        ok[i] = e < E;
        pv[i] = ok[i] ? pc[e] : 0u;
        dd[i] = ok[i] ? dst_idx[e] : 0;
        ss[i] = ok[i] ? src_idx[e] : 0;
    }
    unsigned rp[PL_EPT];
#pragma unroll
    for (int i = 0; i < PL_EPT; i++)
        rp[i] = ok[i] ? rowptr[dd[i]] : 0u;
#pragma unroll
    for (int i = 0; i < PL_EPT; i++) {
        if (!ok[i]) continue;
        unsigned pos = pv[i] & 0x3FFFFFFFu;
        unsigned code = pv[i] & 0xC0000000u;
        src_packed[rp[i] + pos] = (unsigned)ss[i] | code;
    }
}

// ---------------------------------------------------------------------------
// Pass 4: one wave per dst. Phase A: compute 4 signed weights sgn*ex once per
// edge + stash {weights, src} in LDS + esum; butterfly. Phase B: 8-way ILP,
// LDS-fed, fp16 hp gather, one normalize, one 256B store.
// ---------------------------------------------------------------------------
__global__ __launch_bounds__(256) void dst_gather_kernel(
    const unsigned* __restrict__ rowptr,
    const unsigned* __restrict__ src_packed,
    const float* __restrict__ a_src, const float* __restrict__ a_dst,
    const float* __restrict__ b_a,
    const __half* __restrict__ hp,
    float* __restrict__ out, int N)
{
    __shared__ float sw[4][CAP * 4];     // [wave][slot*4+head] = sgn*ex
    __shared__ unsigned ssrc[4][CAP];    // [wave][slot] = src index

    int tid = threadIdx.x;
    int wslot = tid >> 6;
    int lane = tid & 63;
    int q = lane >> 4;
    int d = (blockIdx.x * 256 + tid) >> 6;
    bool valid = d < N;

    unsigned start = 0, end = 0;
    float ba = b_a[0];
    float4 ad4 = make_float4(0.f, 0.f, 0.f, 0.f);
    if (valid) {
        start = rowptr[d];
        end = rowptr[d + 1];
        ad4 = *reinterpret_cast<const float4*>(a_dst + (size_t)d * HEADS);
    }
    float adq = (q == 0) ? ad4.x : (q == 1) ? ad4.y : (q == 2) ? ad4.z : ad4.w;

    // Phase A
    float4 p = make_float4(0.f, 0.f, 0.f, 0.f);
    if (valid) {
        for (unsigned i = start + lane; i < end; i += 64) {
            unsigned sp = src_packed[i];
            unsigned s = sp & 0x3FFFFFFFu;
            unsigned c = sp >> 30;
            float sgn = (c == 0u) ? 1.f : (c == 1u ? -1.f : 0.f);
            float4 as4 = *reinterpret_cast<const float4*>(a_src + (size_t)s * HEADS);
            float ap0 = fmaf(sgn, as4.x, ad4.x) + ba;
            float ap1 = fmaf(sgn, as4.y, ad4.y) + ba;
            float ap2 = fmaf(sgn, as4.z, ad4.z) + ba;
            float ap3 = fmaf(sgn, as4.w, ad4.w) + ba;
            float e0 = expf(ap0 > 0.f ? ap0 : 0.01f * ap0);
            float e1 = expf(ap1 > 0.f ? ap1 : 0.01f * ap1);
            float e2 = expf(ap2 > 0.f ? ap2 : 0.01f * ap2);
            float e3 = expf(ap3 > 0.f ? ap3 : 0.01f * ap3);
            p.x += e0; p.y += e1; p.z += e2; p.w += e3;
            unsigned slot = i - start;
            if (slot < CAP) {
                *reinterpret_cast<float4*>(&sw[wslot][slot * 4]) =
                    make_float4(sgn * e0, sgn * e1, sgn * e2, sgn * e3);
                ssrc[wslot][slot] = s;
            }
        }
    }
    __syncthreads();

#pragma unroll
    for (int off = 32; off >= 1; off >>= 1) {
        p.x += __shfl_xor(p.x, off);
        p.y += __shfl_xor(p.y, off);
        p.z += __shfl_xor(p.z, off);
        p.w += __shfl_xor(p.w, off);
    }
    if (!valid) return;

    float esq = (q == 0) ? p.x : (q == 1) ? p.y : (q == 2) ? p.z : p.w;
    float rinv = (end > start) ? (1.0f / esq) : 0.f;

    const float* swb = &sw[wslot][0];
    const unsigned* ssb = &ssrc[wslot][0];
    unsigned cend = min(end, start + CAP);
    unsigned cnt_c = cend - start;

    // Phase B: 8-way ILP over LDS-cached {weight, src}
    float a0 = 0.f, a1 = 0.f, a2 = 0.f, a3 = 0.f;
    unsigned t0 = 0;
    for (; t0 + 8 <= cnt_c; t0 += 8) {
        float w0 = swb[(t0 + 0) * 4 + q], w1 = swb[(t0 + 1) * 4 + q];
        float w2 = swb[(t0 + 2) * 4 + q], w3 = swb[(t0 + 3) * 4 + q];
        float w4 = swb[(t0 + 4) * 4 + q], w5 = swb[(t0 + 5) * 4 + q];
        float w6 = swb[(t0 + 6) * 4 + q], w7 = swb[(t0 + 7) * 4 + q];
        unsigned s0 = ssb[t0 + 0], s1 = ssb[t0 + 1];
        unsigned s2 = ssb[t0 + 2], s3 = ssb[t0 + 3];
        unsigned s4 = ssb[t0 + 4], s5 = ssb[t0 + 5];
        unsigned s6 = ssb[t0 + 6], s7 = ssb[t0 + 7];
        float h0 = __half2float(hp[((size_t)s0 << 6) | (unsigned)lane]);
        float h1 = __half2float(hp[((size_t)s1 << 6) | (unsigned)lane]);
        float h2 = __half2float(hp[((size_t)s2 << 6) | (unsigned)lane]);
        float h3 = __half2float(hp[((size_t)s3 << 6) | (unsigned)lane]);
        float h4 = __half2float(hp[((size_t)s4 << 6) | (unsigned)lane]);
        float h5 = __half2float(hp[((size_t)s5 << 6) | (unsigned)lane]);
        float h6 = __half2float(hp[((size_t)s6 << 6) | (unsigned)lane]);
        float h7 = __half2float(hp[((size_t)s7 << 6) | (unsigned)lane]);
        a0 = fmaf(w0, h0, a0); a1 = fmaf(w1, h1, a1);
        a2 = fmaf(w2, h2, a2); a3 = fmaf(w3, h3, a3);
        a0 = fmaf(w4, h4, a0); a1 = fmaf(w5, h5, a1);
        a2 = fmaf(w6, h6, a2); a3 = fmaf(w7, h7, a3);
    }
    for (; t0 < cnt_c; t0++) {
        float w = swb[t0 * 4 + q];
        unsigned s = ssb[t0];
        a0 = fmaf(w, __half2float(hp[((size_t)s << 6) | (unsigned)lane]), a0);
    }
    // fallback: degree > CAP (never for Poisson(20); correct always)
    for (unsigned i = start + cnt_c; i < end; i++) {
        unsigned sp = src_packed[i];
        unsigned s = sp & 0x3FFFFFFFu;
        unsigned c = sp >> 30;
        float g = (c == 0u) ? 1.f : (c == 1u ? -1.f : 0.f);
        float asv = a_src[s * HEADS + q];
        float ap = fmaf(g, asv, adq) + ba;
        float ev = expf(ap > 0.f ? ap : 0.01f * ap);
        a0 = fmaf(ev * g, __half2float(hp[((size_t)s << 6) | (unsigned)lane]), a0);
    }
    out[((size_t)d << 6) | (unsigned)lane] = ((a0 + a1) + (a2 + a3)) * rinv;
}

// ---------------------------------------------------------------------------
extern "C" void kernel_launch(void* const* d_in, const int* in_sizes, int n_in,
                              void* d_out, int out_size, void* d_ws, size_t ws_size,
                              hipStream_t stream)
{
    const float* h       = (const float*)d_in[0];
    const int*   src_idx = (const int*)d_in[1];
    const int*   dst_idx = (const int*)d_in[2];
    const float* W_w     = (const float*)d_in[3];
    const float* b_w     = (const float*)d_in[4];
    const float* W_a     = (const float*)d_in[5];
    const float* b_a     = (const float*)d_in[6];
    const float* W_d     = (const float*)d_in[7];
    const float* b_d     = (const float*)d_in[8];
    const float* W_f     = (const float*)d_in[9];
    const float* b_f     = (const float*)d_in[10];

    int N = in_sizes[0] / F;
    int E = in_sizes[1];
    int nb = (N + 255) / 256;

    char* ws = (char*)d_ws;
    float*    tfeat = (float*)ws;      ws += (size_t)N * F * 4;        // 12.8MB
    __half*   hp    = (__half*)ws;     ws += (size_t)N * F * 2;        // 6.4MB
    double*   u_arr = (double*)ws;     ws += (size_t)N * 8;            // 0.4MB
    double*   v_arr = (double*)ws;     ws += (size_t)N * 8;            // 0.4MB
    float*    a_src = (float*)ws;      ws += (size_t)N * HEADS * 4;    // 0.8MB
    float*    a_dst = (float*)ws;      ws += (size_t)N * HEADS * 4;    // 0.8MB
    unsigned* cnt   = (unsigned*)ws;   ws += (size_t)N * 4;            // 0.2MB
    unsigned* rowptr= (unsigned*)ws;   ws += ((size_t)N + 4) * 4;      // 0.2MB
    unsigned* bsum  = (unsigned*)ws;   ws += 1024;                     // 1KB
    unsigned* pc    = (unsigned*)ws;   ws += (size_t)E * 4;            // 4MB
    unsigned* src_p = (unsigned*)ws;   ws += (size_t)E * 4;            // 4MB

    float* out = (float*)d_out;

    node_kernel<<<2 * nb, 256, 0, stream>>>(
        h, W_w, b_w, W_a, W_d, b_d, W_f, tfeat, hp, u_arr, v_arr, a_src, a_dst,
        cnt, N, nb);

    count_sign_kernel<<<(E + 256 * CS_EPT - 1) / (256 * CS_EPT), 256, 0, stream>>>(
        src_idx, dst_idx, u_arr, v_arr, tfeat, W_f, b_f, cnt, pc, E);

    scan1_kernel<<<nb, 256, 0, stream>>>(cnt, rowptr, bsum, N);
    scan3_kernel<<<nb, 256, 0, stream>>>(rowptr, bsum, N, E, nb);

    place_kernel<<<(E + 256 * PL_EPT - 1) / (256 * PL_EPT), 256, 0, stream>>>(
        src_idx, dst_idx, pc, rowptr, src_p, E);

    dst_gather_kernel<<<(N * 64 + 255) / 256, 256, 0, stream>>>(
        rowptr, src_p, a_src, a_dst, b_a, hp, out, N);
}

// Round 11
// 138.441 us; speedup vs baseline: 1.1299x; 1.1299x over previous
//
#include <hip/hip_runtime.h>
#include <hip/hip_fp16.h>

constexpr int F  = 64;   // IN_FEATS == ATT_HEADS*H_FEATS
constexpr int HEADS = 4;
constexpr int K_SLOT = 64;   // fixed per-dst slot capacity (deg>64 -> overflow list)

// ---------------------------------------------------------------------------
// Pass 1 (per node), fp32 mirroring numpy BLAS (seq-k FMA from 0, bias after).
// Blocks [0,nb): W_d path (tfeat fp32, u/v fp32 via f64 accum) + zero cnt.
// Blocks [nb,2nb): W_w path (hp fp16, a_src/a_dst fp32).
// ---------------------------------------------------------------------------
__global__ __launch_bounds__(256) void node_kernel(
    const float* __restrict__ h,
    const float* __restrict__ W_w, const float* __restrict__ b_w,
    const float* __restrict__ W_a,
    const float* __restrict__ W_d, const float* __restrict__ b_d,
    const float* __restrict__ W_f,
    float* __restrict__ tfeat, __half* __restrict__ hp,
    float* __restrict__ u_arr, float* __restrict__ v_arr,
    float* __restrict__ a_src, float* __restrict__ a_dst,
    unsigned* __restrict__ cnt, unsigned* __restrict__ of_cnt, int N, int nb)
{
    __shared__ float sWT[F * F];     // [j][k] transposed
    __shared__ float sb[F];
    __shared__ double swfA[F], swfB[F];
    __shared__ float sWa[32];

    int tid = threadIdx.x;
    bool isW = blockIdx.x >= nb;     // W_w path?
    const float* Wsrc = isW ? W_w : W_d;
    for (int i = tid; i < F * F; i += 256) {
        int k = i >> 6, j = i & 63;
        sWT[j * F + k] = Wsrc[i];
    }
    if (tid < F) sb[tid] = isW ? b_w[tid] : b_d[tid];
    if (!isW && tid < F) {
        swfA[tid] = (double)W_f[tid] + (double)W_f[2 * F + tid];
        swfB[tid] = (double)W_f[F + tid] - (double)W_f[2 * F + tid];
    }
    if (isW && tid < 32) sWa[tid] = W_a[tid];
    if (blockIdx.x == 0 && tid == 0) *of_cnt = 0;
    __syncthreads();

    int blk = isW ? (blockIdx.x - nb) : blockIdx.x;
    int n = blk * 256 + tid;
    if (n >= N) return;

    if (!isW) cnt[n] = 0;            // replaces memset dispatch

    float4 hv[16];
    const float4* h4 = reinterpret_cast<const float4*>(h + (size_t)n * F);
#pragma unroll
    for (int i = 0; i < 16; i++) hv[i] = h4[i];

    if (!isW) {
        // ---- W_d path: tfeat row + u,v ----
        double u = 0.0, v = 0.0;
        float4 tq;
        float4* trow = reinterpret_cast<float4*>(tfeat + (size_t)n * F);
#pragma unroll 4
        for (int j = 0; j < F; j++) {
            const float4* row = reinterpret_cast<const float4*>(&sWT[j * F]);
            float t = 0.f;
#pragma unroll
            for (int kk = 0; kk < 16; kk++) {
                float4 w = row[kk];
                float4 x = hv[kk];
                t = fmaf(x.x, w.x, t);
                t = fmaf(x.y, w.y, t);
                t = fmaf(x.z, w.z, t);
                t = fmaf(x.w, w.w, t);
            }
            t = t + sb[j];
            u = fma((double)t, swfA[j], u);
            v = fma((double)t, swfB[j], v);
            if ((j & 3) == 0) tq.x = t;
            else if ((j & 3) == 1) tq.y = t;
            else if ((j & 3) == 2) tq.z = t;
            else { tq.w = t; trow[j >> 2] = tq; }
        }
        u_arr[n] = (float)u;
        v_arr[n] = (float)v;
    } else {
        // ---- W_w path: hp row (fp16) + a_src,a_dst per head ----
        __half2* prow = reinterpret_cast<__half2*>(hp + (size_t)n * F);
#pragma unroll
        for (int qh = 0; qh < 4; qh++) {
            float asq = 0.f, adq = 0.f;
            float pprev = 0.f;
#pragma unroll 4
            for (int jj = 0; jj < 16; jj++) {
                int j = qh * 16 + jj;
                const float4* row = reinterpret_cast<const float4*>(&sWT[j * F]);
                float p = 0.f;
#pragma unroll
                for (int kk = 0; kk < 16; kk++) {
                    float4 w = row[kk];
                    float4 x = hv[kk];
                    p = fmaf(x.x, w.x, p);
                    p = fmaf(x.y, w.y, p);
                    p = fmaf(x.z, w.z, p);
                    p = fmaf(x.w, w.w, p);
                }
                p = p + sb[j];
                asq = fmaf(p, sWa[jj], asq);
                adq = fmaf(p, sWa[16 + jj], adq);
                if ((jj & 1) == 0) pprev = p;
                else prow[j >> 1] = __floats2half2_rn(pprev, p);
            }
            a_src[n * HEADS + qh] = asq;
            a_dst[n * HEADS + qh] = adq;
        }
    }
}

// ---------------------------------------------------------------------------
// Tier-2 sign fallback: literal fp32 192-term sequential FMA in the
// reference's e_feat section order (rare: |fp32 margin| < 1e-4).
// ---------------------------------------------------------------------------
__device__ __noinline__ float tier2_sign(
    const float* __restrict__ tfeat, const float* __restrict__ sWf,
    int s, int d, float bf)
{
    const float4* ts = reinterpret_cast<const float4*>(tfeat + (size_t)s * F);
    const float4* td = reinterpret_cast<const float4*>(tfeat + (size_t)d * F);
    float sv[F];
#pragma unroll
    for (int i = 0; i < 16; i++) {
        float4 a = ts[i];
        sv[4 * i + 0] = a.x; sv[4 * i + 1] = a.y;
        sv[4 * i + 2] = a.z; sv[4 * i + 3] = a.w;
    }
    float acc = 0.f;
#pragma unroll
    for (int j = 0; j < F; j++) acc = fmaf(sv[j], sWf[j], acc);
#pragma unroll
    for (int i = 0; i < 16; i++) {
        float4 a = td[i];
        acc = fmaf(a.x, sWf[F + 4 * i + 0], acc);
        acc = fmaf(a.y, sWf[F + 4 * i + 1], acc);
        acc = fmaf(a.z, sWf[F + 4 * i + 2], acc);
        acc = fmaf(a.w, sWf[F + 4 * i + 3], acc);
    }
#pragma unroll
    for (int i = 0; i < 16; i++) {
        float4 a = td[i];
        acc = fmaf(sv[4 * i + 0] - a.x, sWf[2 * F + 4 * i + 0], acc);
        acc = fmaf(sv[4 * i + 1] - a.y, sWf[2 * F + 4 * i + 1], acc);
        acc = fmaf(sv[4 * i + 2] - a.z, sWf[2 * F + 4 * i + 2], acc);
        acc = fmaf(sv[4 * i + 3] - a.w, sWf[2 * F + 4 * i + 3], acc);
    }
    float sp = acc + bf;
    return (sp > 0.f) ? 1.f : (sp < 0.f ? -1.f : 0.f);
}

// ---------------------------------------------------------------------------
// Fused count + sign + direct slot scatter. 2 edges/thread.
// pos = atomicAdd(cnt[d]); slot[d*64+pos] = src|code<<30  (final location --
// no scan, no place pass). Overflow (deg>64, never for this graph) -> of_list.
// ---------------------------------------------------------------------------
__global__ __launch_bounds__(256) void count_scatter_kernel(
    const int* __restrict__ src_idx, const int* __restrict__ dst_idx,
    const float* __restrict__ u_arr, const float* __restrict__ v_arr,
    const float* __restrict__ tfeat, const float* __restrict__ W_f,
    const float* __restrict__ b_f,
    unsigned* __restrict__ cnt, unsigned* __restrict__ slot,
    unsigned* __restrict__ of_list, unsigned* __restrict__ of_cnt, int E)
{
    __shared__ float sWf[3 * F];
    int tid = threadIdx.x;
    if (tid < 3 * F) sWf[tid] = W_f[tid];
    __syncthreads();

    float bf = b_f[0];
    int e0 = blockIdx.x * 512 + tid;
    int e1 = e0 + 256;
    bool ok0 = e0 < E, ok1 = e1 < E;

    int s0 = 0, d0 = 0, s1 = 0, d1 = 0;
    if (ok0) { s0 = src_idx[e0]; d0 = dst_idx[e0]; }
    if (ok1) { s1 = src_idx[e1]; d1 = dst_idx[e1]; }

    // independent long-latency ops issued up front
    float us0 = ok0 ? u_arr[s0] : 0.f, vd0 = ok0 ? v_arr[d0] : 0.f;
    float us1 = ok1 ? u_arr[s1] : 0.f, vd1 = ok1 ? v_arr[d1] : 0.f;
    unsigned p0 = ok0 ? atomicAdd(&cnt[d0], 1u) : 0u;
    unsigned p1 = ok1 ? atomicAdd(&cnt[d1], 1u) : 0u;

    float m0 = us0 + vd0 + bf;
    float m1 = us1 + vd1 + bf;

    float sg0 = (fabsf(m0) >= 1e-4f) ? ((m0 > 0.f) ? 1.f : -1.f)
                                     : (ok0 ? tier2_sign(tfeat, sWf, s0, d0, bf) : 0.f);
    float sg1 = (fabsf(m1) >= 1e-4f) ? ((m1 > 0.f) ? 1.f : -1.f)
                                     : (ok1 ? tier2_sign(tfeat, sWf, s1, d1, bf) : 0.f);

    if (ok0) {
        unsigned c0 = (sg0 > 0.f) ? 0u : (sg0 < 0.f ? 1u : 2u);
        unsigned val = (unsigned)s0 | (c0 << 30);
        if (p0 < (unsigned)K_SLOT) slot[(size_t)d0 * K_SLOT + p0] = val;
        else {
            unsigned oi = atomicAdd(of_cnt, 1u);
            of_list[2 * oi] = (unsigned)d0;
            of_list[2 * oi + 1] = val;
        }
    }
    if (ok1) {
        unsigned c1 = (sg1 > 0.f) ? 0u : (sg1 < 0.f ? 1u : 2u);
        unsigned val = (unsigned)s1 | (c1 << 30);
        if (p1 < (unsigned)K_SLOT) slot[(size_t)d1 * K_SLOT + p1] = val;
        else {
            unsigned oi = atomicAdd(of_cnt, 1u);
            of_list[2 * oi] = (unsigned)d1;
            of_list[2 * oi + 1] = val;
        }
    }
}

// ---------------------------------------------------------------------------
// Pass 3: one wave per dst, slots at d*64 (no rowptr). Phase A: each lane
// handles one slot (deg<=64): 4 signed weights sgn*ex once per edge, stash
// {weights, src} in LDS, esum partial; butterfly. Phase B: 8-way ILP LDS-fed
// fp16 hp gather; normalize once; one 256B store. Overflow path correct but
// never exercised for this graph.
// ---------------------------------------------------------------------------
__global__ __launch_bounds__(256) void dst_gather_kernel(
    const unsigned* __restrict__ cnt,
    const unsigned* __restrict__ slot,
    const unsigned* __restrict__ of_list, const unsigned* __restrict__ of_cnt,
    const float* __restrict__ a_src, const float* __restrict__ a_dst,
    const float* __restrict__ b_a,
    const __half* __restrict__ hp,
    float* __restrict__ out, int N)
{
    __shared__ float sw[4][K_SLOT * 4];     // [wave][slot*4+head] = sgn*ex
    __shared__ unsigned ssrc[4][K_SLOT];    // [wave][slot] = src index

    int tid = threadIdx.x;
    int wslot = tid >> 6;
    int lane = tid & 63;
    int q = lane >> 4;
    int d = (blockIdx.x * 256 + tid) >> 6;
    bool valid = d < N;

    unsigned deg = 0;
    float ba = b_a[0];
    float4 ad4 = make_float4(0.f, 0.f, 0.f, 0.f);
    if (valid) {
        deg = cnt[d];
        ad4 = *reinterpret_cast<const float4*>(a_dst + (size_t)d * HEADS);
    }
    float adq = (q == 0) ? ad4.x : (q == 1) ? ad4.y : (q == 2) ? ad4.z : ad4.w;
    unsigned mdeg = min(deg, (unsigned)K_SLOT);

    // Phase A: one slot per lane
    float4 p = make_float4(0.f, 0.f, 0.f, 0.f);
    if (valid && lane < (int)mdeg) {
        unsigned sp = slot[(size_t)d * K_SLOT + lane];
        unsigned s = sp & 0x3FFFFFFFu;
        unsigned c = sp >> 30;
        float sgn = (c == 0u) ? 1.f : (c == 1u ? -1.f : 0.f);
        float4 as4 = *reinterpret_cast<const float4*>(a_src + (size_t)s * HEADS);
        float ap0 = fmaf(sgn, as4.x, ad4.x) + ba;
        float ap1 = fmaf(sgn, as4.y, ad4.y) + ba;
        float ap2 = fmaf(sgn, as4.z, ad4.z) + ba;
        float ap3 = fmaf(sgn, as4.w, ad4.w) + ba;
        float e0 = expf(ap0 > 0.f ? ap0 : 0.01f * ap0);
        float e1 = expf(ap1 > 0.f ? ap1 : 0.01f * ap1);
        float e2 = expf(ap2 > 0.f ? ap2 : 0.01f * ap2);
        float e3 = expf(ap3 > 0.f ? ap3 : 0.01f * ap3);
        p = make_float4(e0, e1, e2, e3);
        *reinterpret_cast<float4*>(&sw[wslot][lane * 4]) =
            make_float4(sgn * e0, sgn * e1, sgn * e2, sgn * e3);
        ssrc[wslot][lane] = s;
    }
    // overflow esum contributions (deg > 64; never here, correct always)
    if (valid && deg > (unsigned)K_SLOT) {
        unsigned on = *of_cnt;
        for (unsigned i = lane; i < on; i += 64) {
            if (of_list[2 * i] == (unsigned)d) {
                unsigned sp = of_list[2 * i + 1];
                unsigned s = sp & 0x3FFFFFFFu;
                unsigned c = sp >> 30;
                float sgn = (c == 0u) ? 1.f : (c == 1u ? -1.f : 0.f);
                float4 as4 = *reinterpret_cast<const float4*>(a_src + (size_t)s * HEADS);
                float ap0 = fmaf(sgn, as4.x, ad4.x) + ba;
                float ap1 = fmaf(sgn, as4.y, ad4.y) + ba;
                float ap2 = fmaf(sgn, as4.z, ad4.z) + ba;
                float ap3 = fmaf(sgn, as4.w, ad4.w) + ba;
                p.x += expf(ap0 > 0.f ? ap0 : 0.01f * ap0);
                p.y += expf(ap1 > 0.f ? ap1 : 0.01f * ap1);
                p.z += expf(ap2 > 0.f ? ap2 : 0.01f * ap2);
                p.w += expf(ap3 > 0.f ? ap3 : 0.01f * ap3);
            }
        }
    }
    __syncthreads();

#pragma unroll
    for (int off = 32; off >= 1; off >>= 1) {
        p.x += __shfl_xor(p.x, off);
        p.y += __shfl_xor(p.y, off);
        p.z += __shfl_xor(p.z, off);
        p.w += __shfl_xor(p.w, off);
    }
    if (!valid) return;

    float esq = (q == 0) ? p.x : (q == 1) ? p.y : (q == 2) ? p.z : p.w;
    float rinv = (deg > 0) ? (1.0f / esq) : 0.f;

    const float* swb = &sw[wslot][0];
    const unsigned* ssb = &ssrc[wslot][0];

    // Phase B: 8-way ILP over LDS-cached {weight, src}
    float a0 = 0.f, a1 = 0.f, a2 = 0.f, a3 = 0.f;
    unsigned t0 = 0;
    for (; t0 + 8 <= mdeg; t0 += 8) {
        float w0 = swb[(t0 + 0) * 4 + q], w1 = swb[(t0 + 1) * 4 + q];
        float w2 = swb[(t0 + 2) * 4 + q], w3 = swb[(t0 + 3) * 4 + q];
        float w4 = swb[(t0 + 4) * 4 + q], w5 = swb[(t0 + 5) * 4 + q];
        float w6 = swb[(t0 + 6) * 4 + q], w7 = swb[(t0 + 7) * 4 + q];
        unsigned s0 = ssb[t0 + 0], s1 = ssb[t0 + 1];
        unsigned s2 = ssb[t0 + 2], s3 = ssb[t0 + 3];
        unsigned s4 = ssb[t0 + 4], s5 = ssb[t0 + 5];
        unsigned s6 = ssb[t0 + 6], s7 = ssb[t0 + 7];
        float h0 = __half2float(hp[((size_t)s0 << 6) | (unsigned)lane]);
        float h1 = __half2float(hp[((size_t)s1 << 6) | (unsigned)lane]);
        float h2 = __half2float(hp[((size_t)s2 << 6) | (unsigned)lane]);
        float h3 = __half2float(hp[((size_t)s3 << 6) | (unsigned)lane]);
        float h4 = __half2float(hp[((size_t)s4 << 6) | (unsigned)lane]);
        float h5 = __half2float(hp[((size_t)s5 << 6) | (unsigned)lane]);
        float h6 = __half2float(hp[((size_t)s6 << 6) | (unsigned)lane]);
        float h7 = __half2float(hp[((size_t)s7 << 6) | (unsigned)lane]);
        a0 = fmaf(w0, h0, a0); a1 = fmaf(w1, h1, a1);
        a2 = fmaf(w2, h2, a2); a3 = fmaf(w3, h3, a3);
        a0 = fmaf(w4, h4, a0); a1 = fmaf(w5, h5, a1);
        a2 = fmaf(w6, h6, a2); a3 = fmaf(w7, h7, a3);
    }
    for (; t0 < mdeg; t0++) {
        float w = swb[t0 * 4 + q];
        unsigned s = ssb[t0];
        a0 = fmaf(w, __half2float(hp[((size_t)s << 6) | (unsigned)lane]), a0);
    }
    // overflow Phase B (never exercised for this graph)
    if (deg > (unsigned)K_SLOT) {
        unsigned on = *of_cnt;
        for (unsigned i = 0; i < on; i++) {
            if (of_list[2 * i] == (unsigned)d) {
                unsigned sp = of_list[2 * i + 1];
                unsigned s = sp & 0x3FFFFFFFu;
                unsigned c = sp >> 30;
                float g = (c == 0u) ? 1.f : (c == 1u ? -1.f : 0.f);
                float asv = a_src[s * HEADS + q];
                float ap = fmaf(g, asv, adq) + ba;
                float ev = expf(ap > 0.f ? ap : 0.01f * ap);
                a0 = fmaf(ev * g, __half2float(hp[((size_t)s << 6) | (unsigned)lane]), a0);
            }
        }
    }
    out[((size_t)d << 6) | (unsigned)lane] = ((a0 + a1) + (a2 + a3)) * rinv;
}

// ---------------------------------------------------------------------------
extern "C" void kernel_launch(void* const* d_in, const int* in_sizes, int n_in,
                              void* d_out, int out_size, void* d_ws, size_t ws_size,
                              hipStream_t stream)
{
    const float* h       = (const float*)d_in[0];
    const int*   src_idx = (const int*)d_in[1];
    const int*   dst_idx = (const int*)d_in[2];
    const float* W_w     = (const float*)d_in[3];
    const float* b_w     = (const float*)d_in[4];
    const float* W_a     = (const float*)d_in[5];
    const float* b_a     = (const float*)d_in[6];
    const float* W_d     = (const float*)d_in[7];
    const float* b_d     = (const float*)d_in[8];
    const float* W_f     = (const float*)d_in[9];
    const float* b_f     = (const float*)d_in[10];

    int N = in_sizes[0] / F;
    int E = in_sizes[1];
    int nb = (N + 255) / 256;

    char* ws = (char*)d_ws;
    float*    tfeat  = (float*)ws;     ws += (size_t)N * F * 4;          // 12.8MB
    __half*   hp     = (__half*)ws;    ws += (size_t)N * F * 2;          // 6.4MB
    float*    u_arr  = (float*)ws;     ws += (size_t)N * 4;              // 0.2MB
    float*    v_arr  = (float*)ws;     ws += (size_t)N * 4;              // 0.2MB
    float*    a_src  = (float*)ws;     ws += (size_t)N * HEADS * 4;      // 0.8MB
    float*    a_dst  = (float*)ws;     ws += (size_t)N * HEADS * 4;      // 0.8MB
    unsigned* cnt    = (unsigned*)ws;  ws += (size_t)N * 4;              // 0.2MB
    unsigned* of_cnt = (unsigned*)ws;  ws += 64;                         // 64B
    unsigned* slot   = (unsigned*)ws;  ws += (size_t)N * K_SLOT * 4;     // 12.8MB
    unsigned* of_list= (unsigned*)ws;  ws += (size_t)E * 8;              // 8MB

    float* out = (float*)d_out;

    node_kernel<<<2 * nb, 256, 0, stream>>>(
        h, W_w, b_w, W_a, W_d, b_d, W_f, tfeat, hp, u_arr, v_arr, a_src, a_dst,
        cnt, of_cnt, N, nb);

    count_scatter_kernel<<<(E + 511) / 512, 256, 0, stream>>>(
        src_idx, dst_idx, u_arr, v_arr, tfeat, W_f, b_f,
        cnt, slot, of_list, of_cnt, E);

    dst_gather_kernel<<<(N * 64 + 255) / 256, 256, 0, stream>>>(
        cnt, slot, of_list, of_cnt, a_src, a_dst, b_a, hp, out, N);
}

// Round 12
// 136.542 us; speedup vs baseline: 1.1456x; 1.0139x over previous
//
#include <hip/hip_runtime.h>
#include <hip/hip_fp16.h>

constexpr int F  = 64;   // IN_FEATS == ATT_HEADS*H_FEATS
constexpr int HEADS = 4;
constexpr int K_SLOT = 64;    // fixed per-dst slot capacity (deg>64 -> overflow)
constexpr int CPAD = 16;      // cnt padded: one counter per 64B line

// ---------------------------------------------------------------------------
// K1 (per node): W_d path only. tfeat fp32 (BLAS-order), u/v fp32; zero cnt.
// ---------------------------------------------------------------------------
__global__ __launch_bounds__(256) void node_wd_kernel(
    const float* __restrict__ h,
    const float* __restrict__ W_d, const float* __restrict__ b_d,
    const float* __restrict__ W_f,
    float* __restrict__ tfeat,
    float* __restrict__ u_arr, float* __restrict__ v_arr,
    unsigned* __restrict__ cnt, unsigned* __restrict__ of_cnt, int N)
{
    __shared__ float sWT[F * F];     // [j][k] transposed
    __shared__ float sb[F];
    __shared__ double swfA[F], swfB[F];

    int tid = threadIdx.x;
    for (int i = tid; i < F * F; i += 256) {
        int k = i >> 6, j = i & 63;
        sWT[j * F + k] = W_d[i];
    }
    if (tid < F) {
        sb[tid] = b_d[tid];
        swfA[tid] = (double)W_f[tid] + (double)W_f[2 * F + tid];
        swfB[tid] = (double)W_f[F + tid] - (double)W_f[2 * F + tid];
    }
    if (blockIdx.x == 0 && tid == 0) *of_cnt = 0;
    __syncthreads();

    int n = blockIdx.x * 256 + tid;
    if (n >= N) return;

    cnt[(size_t)n * CPAD] = 0;

    float4 hv[16];
    const float4* h4 = reinterpret_cast<const float4*>(h + (size_t)n * F);
#pragma unroll
    for (int i = 0; i < 16; i++) hv[i] = h4[i];

    double u = 0.0, v = 0.0;
    float4 tq;
    float4* trow = reinterpret_cast<float4*>(tfeat + (size_t)n * F);
#pragma unroll 4
    for (int j = 0; j < F; j++) {
        const float4* row = reinterpret_cast<const float4*>(&sWT[j * F]);
        float t = 0.f;
#pragma unroll
        for (int kk = 0; kk < 16; kk++) {
            float4 w = row[kk];
            float4 x = hv[kk];
            t = fmaf(x.x, w.x, t);
            t = fmaf(x.y, w.y, t);
            t = fmaf(x.z, w.z, t);
            t = fmaf(x.w, w.w, t);
        }
        t = t + sb[j];
        u = fma((double)t, swfA[j], u);
        v = fma((double)t, swfB[j], v);
        if ((j & 3) == 0) tq.x = t;
        else if ((j & 3) == 1) tq.y = t;
        else if ((j & 3) == 2) tq.z = t;
        else { tq.w = t; trow[j >> 2] = tq; }
    }
    u_arr[n] = (float)u;
    v_arr[n] = (float)v;
}

// ---------------------------------------------------------------------------
// Tier-2 sign fallback: literal fp32 192-term sequential FMA in the
// reference's e_feat section order (rare: |fp32 margin| < 1e-4).
// ---------------------------------------------------------------------------
__device__ __noinline__ float tier2_sign(
    const float* __restrict__ tfeat, const float* __restrict__ sWf,
    int s, int d, float bf)
{
    const float4* ts = reinterpret_cast<const float4*>(tfeat + (size_t)s * F);
    const float4* td = reinterpret_cast<const float4*>(tfeat + (size_t)d * F);
    float sv[F];
#pragma unroll
    for (int i = 0; i < 16; i++) {
        float4 a = ts[i];
        sv[4 * i + 0] = a.x; sv[4 * i + 1] = a.y;
        sv[4 * i + 2] = a.z; sv[4 * i + 3] = a.w;
    }
    float acc = 0.f;
#pragma unroll
    for (int j = 0; j < F; j++) acc = fmaf(sv[j], sWf[j], acc);
#pragma unroll
    for (int i = 0; i < 16; i++) {
        float4 a = td[i];
        acc = fmaf(a.x, sWf[F + 4 * i + 0], acc);
        acc = fmaf(a.y, sWf[F + 4 * i + 1], acc);
        acc = fmaf(a.z, sWf[F + 4 * i + 2], acc);
        acc = fmaf(a.w, sWf[F + 4 * i + 3], acc);
    }
#pragma unroll
    for (int i = 0; i < 16; i++) {
        float4 a = td[i];
        acc = fmaf(sv[4 * i + 0] - a.x, sWf[2 * F + 4 * i + 0], acc);
        acc = fmaf(sv[4 * i + 1] - a.y, sWf[2 * F + 4 * i + 1], acc);
        acc = fmaf(sv[4 * i + 2] - a.z, sWf[2 * F + 4 * i + 2], acc);
        acc = fmaf(sv[4 * i + 3] - a.w, sWf[2 * F + 4 * i + 3], acc);
    }
    float sp = acc + bf;
    return (sp > 0.f) ? 1.f : (sp < 0.f ? -1.f : 0.f);
}

// ---------------------------------------------------------------------------
// K2 fused: blocks [0,nbw): node W_w path (hp fp16, a_src/a_dst).
//           blocks [nbw,..): edge count+sign+slot scatter (2 edges/thread).
// Independent work co-resident: GEMM fills VALU under the latency-bound
// edge blocks.
// ---------------------------------------------------------------------------
__global__ __launch_bounds__(256) void ww_count_scatter_kernel(
    const float* __restrict__ h,
    const float* __restrict__ W_w, const float* __restrict__ b_w,
    const float* __restrict__ W_a,
    __half* __restrict__ hp,
    float* __restrict__ a_src, float* __restrict__ a_dst,
    const int* __restrict__ src_idx, const int* __restrict__ dst_idx,
    const float* __restrict__ u_arr, const float* __restrict__ v_arr,
    const float* __restrict__ tfeat, const float* __restrict__ W_f,
    const float* __restrict__ b_f,
    unsigned* __restrict__ cnt, unsigned* __restrict__ slot,
    unsigned* __restrict__ of_list, unsigned* __restrict__ of_cnt,
    int N, int E, int nbw)
{
    __shared__ float sWT[F * F];   // W_w blocks: transposed weights; edge blocks: sWf in [0,192)
    __shared__ float sb[F];
    __shared__ float sWa[32];

    int tid = threadIdx.x;

    if (blockIdx.x < nbw) {
        // ---- node W_w path ----
        for (int i = tid; i < F * F; i += 256) {
            int k = i >> 6, j = i & 63;
            sWT[j * F + k] = W_w[i];
        }
        if (tid < F) sb[tid] = b_w[tid];
        if (tid < 32) sWa[tid] = W_a[tid];
        __syncthreads();

        int n = blockIdx.x * 256 + tid;
        if (n >= N) return;

        float4 hv[16];
        const float4* h4 = reinterpret_cast<const float4*>(h + (size_t)n * F);
#pragma unroll
        for (int i = 0; i < 16; i++) hv[i] = h4[i];

        __half2* prow = reinterpret_cast<__half2*>(hp + (size_t)n * F);
#pragma unroll
        for (int qh = 0; qh < 4; qh++) {
            float asq = 0.f, adq = 0.f;
            float pprev = 0.f;
#pragma unroll 4
            for (int jj = 0; jj < 16; jj++) {
                int j = qh * 16 + jj;
                const float4* row = reinterpret_cast<const float4*>(&sWT[j * F]);
                float p = 0.f;
#pragma unroll
                for (int kk = 0; kk < 16; kk++) {
                    float4 w = row[kk];
                    float4 x = hv[kk];
                    p = fmaf(x.x, w.x, p);
                    p = fmaf(x.y, w.y, p);
                    p = fmaf(x.z, w.z, p);
                    p = fmaf(x.w, w.w, p);
                }
                p = p + sb[j];
                asq = fmaf(p, sWa[jj], asq);
                adq = fmaf(p, sWa[16 + jj], adq);
                if ((jj & 1) == 0) pprev = p;
                else prow[j >> 1] = __floats2half2_rn(pprev, p);
            }
            a_src[n * HEADS + qh] = asq;
            a_dst[n * HEADS + qh] = adq;
        }
        return;
    }

    // ---- edge path ----
    float* sWf = sWT;   // reuse first 192 floats
    if (tid < 3 * F) sWf[tid] = W_f[tid];
    __syncthreads();

    float bf = b_f[0];
    int eb = blockIdx.x - nbw;
    int e0 = eb * 512 + tid;
    int e1 = e0 + 256;
    bool ok0 = e0 < E, ok1 = e1 < E;

    int s0 = 0, d0 = 0, s1 = 0, d1 = 0;
    if (ok0) { s0 = src_idx[e0]; d0 = dst_idx[e0]; }
    if (ok1) { s1 = src_idx[e1]; d1 = dst_idx[e1]; }

    // independent long-latency ops issued up front
    float us0 = ok0 ? u_arr[s0] : 0.f, vd0 = ok0 ? v_arr[d0] : 0.f;
    float us1 = ok1 ? u_arr[s1] : 0.f, vd1 = ok1 ? v_arr[d1] : 0.f;
    unsigned p0 = ok0 ? atomicAdd(&cnt[(size_t)d0 * CPAD], 1u) : 0u;
    unsigned p1 = ok1 ? atomicAdd(&cnt[(size_t)d1 * CPAD], 1u) : 0u;

    float m0 = us0 + vd0 + bf;
    float m1 = us1 + vd1 + bf;

    float sg0 = (fabsf(m0) >= 1e-4f) ? ((m0 > 0.f) ? 1.f : -1.f)
                                     : (ok0 ? tier2_sign(tfeat, sWf, s0, d0, bf) : 0.f);
    float sg1 = (fabsf(m1) >= 1e-4f) ? ((m1 > 0.f) ? 1.f : -1.f)
                                     : (ok1 ? tier2_sign(tfeat, sWf, s1, d1, bf) : 0.f);

    if (ok0) {
        unsigned c0 = (sg0 > 0.f) ? 0u : (sg0 < 0.f ? 1u : 2u);
        unsigned val = (unsigned)s0 | (c0 << 30);
        if (p0 < (unsigned)K_SLOT) slot[(size_t)d0 * K_SLOT + p0] = val;
        else {
            unsigned oi = atomicAdd(of_cnt, 1u);
            of_list[2 * oi] = (unsigned)d0;
            of_list[2 * oi + 1] = val;
        }
    }
    if (ok1) {
        unsigned c1 = (sg1 > 0.f) ? 0u : (sg1 < 0.f ? 1u : 2u);
        unsigned val = (unsigned)s1 | (c1 << 30);
        if (p1 < (unsigned)K_SLOT) slot[(size_t)d1 * K_SLOT + p1] = val;
        else {
            unsigned oi = atomicAdd(of_cnt, 1u);
            of_list[2 * oi] = (unsigned)d1;
            of_list[2 * oi + 1] = val;
        }
    }
}

// ---------------------------------------------------------------------------
// K3: one wave per dst, slots at d*64. Phase A: one slot per lane (deg<=64):
// 4 signed weights sgn*ex once per edge, stash {weights, src} in LDS, esum
// partial; butterfly. Phase B: 8-way ILP LDS-fed fp16 hp gather; normalize
// once; one 256B store. Overflow path correct but never exercised.
// ---------------------------------------------------------------------------
__global__ __launch_bounds__(256) void dst_gather_kernel(
    const unsigned* __restrict__ cnt,
    const unsigned* __restrict__ slot,
    const unsigned* __restrict__ of_list, const unsigned* __restrict__ of_cnt,
    const float* __restrict__ a_src, const float* __restrict__ a_dst,
    const float* __restrict__ b_a,
    const __half* __restrict__ hp,
    float* __restrict__ out, int N)
{
    __shared__ float sw[4][K_SLOT * 4];     // [wave][slot*4+head] = sgn*ex
    __shared__ unsigned ssrc[4][K_SLOT];    // [wave][slot] = src index

    int tid = threadIdx.x;
    int wslot = tid >> 6;
    int lane = tid & 63;
    int q = lane >> 4;
    int d = (blockIdx.x * 256 + tid) >> 6;
    bool valid = d < N;

    unsigned deg = 0;
    float ba = b_a[0];
    float4 ad4 = make_float4(0.f, 0.f, 0.f, 0.f);
    if (valid) {
        deg = cnt[(size_t)d * CPAD];
        ad4 = *reinterpret_cast<const float4*>(a_dst + (size_t)d * HEADS);
    }
    float adq = (q == 0) ? ad4.x : (q == 1) ? ad4.y : (q == 2) ? ad4.z : ad4.w;
    unsigned mdeg = min(deg, (unsigned)K_SLOT);

    // Phase A: one slot per lane
    float4 p = make_float4(0.f, 0.f, 0.f, 0.f);
    if (valid && lane < (int)mdeg) {
        unsigned sp = slot[(size_t)d * K_SLOT + lane];
        unsigned s = sp & 0x3FFFFFFFu;
        unsigned c = sp >> 30;
        float sgn = (c == 0u) ? 1.f : (c == 1u ? -1.f : 0.f);
        float4 as4 = *reinterpret_cast<const float4*>(a_src + (size_t)s * HEADS);
        float ap0 = fmaf(sgn, as4.x, ad4.x) + ba;
        float ap1 = fmaf(sgn, as4.y, ad4.y) + ba;
        float ap2 = fmaf(sgn, as4.z, ad4.z) + ba;
        float ap3 = fmaf(sgn, as4.w, ad4.w) + ba;
        float e0 = expf(ap0 > 0.f ? ap0 : 0.01f * ap0);
        float e1 = expf(ap1 > 0.f ? ap1 : 0.01f * ap1);
        float e2 = expf(ap2 > 0.f ? ap2 : 0.01f * ap2);
        float e3 = expf(ap3 > 0.f ? ap3 : 0.01f * ap3);
        p = make_float4(e0, e1, e2, e3);
        *reinterpret_cast<float4*>(&sw[wslot][lane * 4]) =
            make_float4(sgn * e0, sgn * e1, sgn * e2, sgn * e3);
        ssrc[wslot][lane] = s;
    }
    // overflow esum contributions (deg > 64; never here, correct always)
    if (valid && deg > (unsigned)K_SLOT) {
        unsigned on = *of_cnt;
        for (unsigned i = lane; i < on; i += 64) {
            if (of_list[2 * i] == (unsigned)d) {
                unsigned sp = of_list[2 * i + 1];
                unsigned s = sp & 0x3FFFFFFFu;
                unsigned c = sp >> 30;
                float sgn = (c == 0u) ? 1.f : (c == 1u ? -1.f : 0.f);
                float4 as4 = *reinterpret_cast<const float4*>(a_src + (size_t)s * HEADS);
                float ap0 = fmaf(sgn, as4.x, ad4.x) + ba;
                float ap1 = fmaf(sgn, as4.y, ad4.y) + ba;
                float ap2 = fmaf(sgn, as4.z, ad4.z) + ba;
                float ap3 = fmaf(sgn, as4.w, ad4.w) + ba;
                p.x += expf(ap0 > 0.f ? ap0 : 0.01f * ap0);
                p.y += expf(ap1 > 0.f ? ap1 : 0.01f * ap1);
                p.z += expf(ap2 > 0.f ? ap2 : 0.01f * ap2);
                p.w += expf(ap3 > 0.f ? ap3 : 0.01f * ap3);
            }
        }
    }
    __syncthreads();

#pragma unroll
    for (int off = 32; off >= 1; off >>= 1) {
        p.x += __shfl_xor(p.x, off);
        p.y += __shfl_xor(p.y, off);
        p.z += __shfl_xor(p.z, off);
        p.w += __shfl_xor(p.w, off);
    }
    if (!valid) return;

    float esq = (q == 0) ? p.x : (q == 1) ? p.y : (q == 2) ? p.z : p.w;
    float rinv = (deg > 0) ? (1.0f / esq) : 0.f;

    const float* swb = &sw[wslot][0];
    const unsigned* ssb = &ssrc[wslot][0];

    // Phase B: 8-way ILP over LDS-cached {weight, src}
    float a0 = 0.f, a1 = 0.f, a2 = 0.f, a3 = 0.f;
    unsigned t0 = 0;
    for (; t0 + 8 <= mdeg; t0 += 8) {
        float w0 = swb[(t0 + 0) * 4 + q], w1 = swb[(t0 + 1) * 4 + q];
        float w2 = swb[(t0 + 2) * 4 + q], w3 = swb[(t0 + 3) * 4 + q];
        float w4 = swb[(t0 + 4) * 4 + q], w5 = swb[(t0 + 5) * 4 + q];
        float w6 = swb[(t0 + 6) * 4 + q], w7 = swb[(t0 + 7) * 4 + q];
        unsigned s0 = ssb[t0 + 0], s1 = ssb[t0 + 1];
        unsigned s2 = ssb[t0 + 2], s3 = ssb[t0 + 3];
        unsigned s4 = ssb[t0 + 4], s5 = ssb[t0 + 5];
        unsigned s6 = ssb[t0 + 6], s7 = ssb[t0 + 7];
        float h0 = __half2float(hp[((size_t)s0 << 6) | (unsigned)lane]);
        float h1 = __half2float(hp[((size_t)s1 << 6) | (unsigned)lane]);
        float h2 = __half2float(hp[((size_t)s2 << 6) | (unsigned)lane]);
        float h3 = __half2float(hp[((size_t)s3 << 6) | (unsigned)lane]);
        float h4 = __half2float(hp[((size_t)s4 << 6) | (unsigned)lane]);
        float h5 = __half2float(hp[((size_t)s5 << 6) | (unsigned)lane]);
        float h6 = __half2float(hp[((size_t)s6 << 6) | (unsigned)lane]);
        float h7 = __half2float(hp[((size_t)s7 << 6) | (unsigned)lane]);
        a0 = fmaf(w0, h0, a0); a1 = fmaf(w1, h1, a1);
        a2 = fmaf(w2, h2, a2); a3 = fmaf(w3, h3, a3);
        a0 = fmaf(w4, h4, a0); a1 = fmaf(w5, h5, a1);
        a2 = fmaf(w6, h6, a2); a3 = fmaf(w7, h7, a3);
    }
    for (; t0 < mdeg; t0++) {
        float w = swb[t0 * 4 + q];
        unsigned s = ssb[t0];
        a0 = fmaf(w, __half2float(hp[((size_t)s << 6) | (unsigned)lane]), a0);
    }
    // overflow Phase B (never exercised for this graph)
    if (deg > (unsigned)K_SLOT) {
        unsigned on = *of_cnt;
        for (unsigned i = 0; i < on; i++) {
            if (of_list[2 * i] == (unsigned)d) {
                unsigned sp = of_list[2 * i + 1];
                unsigned s = sp & 0x3FFFFFFFu;
                unsigned c = sp >> 30;
                float g = (c == 0u) ? 1.f : (c == 1u ? -1.f : 0.f);
                float asv = a_src[s * HEADS + q];
                float ap = fmaf(g, asv, adq) + ba;
                float ev = expf(ap > 0.f ? ap : 0.01f * ap);
                a0 = fmaf(ev * g, __half2float(hp[((size_t)s << 6) | (unsigned)lane]), a0);
            }
        }
    }
    out[((size_t)d << 6) | (unsigned)lane] = ((a0 + a1) + (a2 + a3)) * rinv;
}

// ---------------------------------------------------------------------------
extern "C" void kernel_launch(void* const* d_in, const int* in_sizes, int n_in,
                              void* d_out, int out_size, void* d_ws, size_t ws_size,
                              hipStream_t stream)
{
    const float* h       = (const float*)d_in[0];
    const int*   src_idx = (const int*)d_in[1];
    const int*   dst_idx = (const int*)d_in[2];
    const float* W_w     = (const float*)d_in[3];
    const float* b_w     = (const float*)d_in[4];
    const float* W_a     = (const float*)d_in[5];
    const float* b_a     = (const float*)d_in[6];
    const float* W_d     = (const float*)d_in[7];
    const float* b_d     = (const float*)d_in[8];
    const float* W_f     = (const float*)d_in[9];
    const float* b_f     = (const float*)d_in[10];

    int N = in_sizes[0] / F;
    int E = in_sizes[1];
    int nb = (N + 255) / 256;
    int neb = (E + 511) / 512;

    char* ws = (char*)d_ws;
    float*    tfeat  = (float*)ws;     ws += (size_t)N * F * 4;          // 12.8MB
    __half*   hp     = (__half*)ws;    ws += (size_t)N * F * 2;          // 6.4MB
    float*    u_arr  = (float*)ws;     ws += (size_t)N * 4;              // 0.2MB
    float*    v_arr  = (float*)ws;     ws += (size_t)N * 4;              // 0.2MB
    float*    a_src  = (float*)ws;     ws += (size_t)N * HEADS * 4;      // 0.8MB
    float*    a_dst  = (float*)ws;     ws += (size_t)N * HEADS * 4;      // 0.8MB
    unsigned* cnt    = (unsigned*)ws;  ws += (size_t)N * CPAD * 4;       // 3.2MB
    unsigned* of_cnt = (unsigned*)ws;  ws += 64;                         // 64B
    unsigned* slot   = (unsigned*)ws;  ws += (size_t)N * K_SLOT * 4;     // 12.8MB
    unsigned* of_list= (unsigned*)ws;  ws += (size_t)E * 8;              // 8MB

    float* out = (float*)d_out;

    node_wd_kernel<<<nb, 256, 0, stream>>>(
        h, W_d, b_d, W_f, tfeat, u_arr, v_arr, cnt, of_cnt, N);

    ww_count_scatter_kernel<<<nb + neb, 256, 0, stream>>>(
        h, W_w, b_w, W_a, hp, a_src, a_dst,
        src_idx, dst_idx, u_arr, v_arr, tfeat, W_f, b_f,
        cnt, slot, of_list, of_cnt, N, E, nb);

    dst_gather_kernel<<<(N * 64 + 255) / 256, 256, 0, stream>>>(
        cnt, slot, of_list, of_cnt, a_src, a_dst, b_a, hp, out, N);
}

// Round 13
// 130.063 us; speedup vs baseline: 1.2027x; 1.0498x over previous
//
#include <hip/hip_runtime.h>
#include <hip/hip_fp16.h>

constexpr int F  = 64;   // IN_FEATS == ATT_HEADS*H_FEATS
constexpr int HEADS = 4;
constexpr int SHARDS = 8;    // one slot/counter shard per XCD
constexpr int CAPS = 16;     // per-shard per-dst slot capacity (overflow -> of_list)
constexpr int MAXDEG = 64;   // per-wave LDS slots in gather

// ---------------------------------------------------------------------------
// K1 (per node): W_d path. tfeat fp32 (BLAS-order), u/v fp32; zero cnt shards.
// ---------------------------------------------------------------------------
__global__ __launch_bounds__(256) void node_wd_kernel(
    const float* __restrict__ h,
    const float* __restrict__ W_d, const float* __restrict__ b_d,
    const float* __restrict__ W_f,
    float* __restrict__ tfeat,
    float* __restrict__ u_arr, float* __restrict__ v_arr,
    unsigned* __restrict__ cnt, unsigned* __restrict__ of_cnt, int N)
{
    __shared__ float sWT[F * F];     // [j][k] transposed
    __shared__ float sb[F];
    __shared__ double swfA[F], swfB[F];

    int tid = threadIdx.x;
    for (int i = tid; i < F * F; i += 256) {
        int k = i >> 6, j = i & 63;
        sWT[j * F + k] = W_d[i];
    }
    if (tid < F) {
        sb[tid] = b_d[tid];
        swfA[tid] = (double)W_f[tid] + (double)W_f[2 * F + tid];
        swfB[tid] = (double)W_f[F + tid] - (double)W_f[2 * F + tid];
    }
    if (blockIdx.x == 0 && tid == 0) *of_cnt = 0;
    __syncthreads();

    int n = blockIdx.x * 256 + tid;
    if (n >= N) return;

#pragma unroll
    for (int x = 0; x < SHARDS; x++) cnt[(size_t)x * N + n] = 0;

    float4 hv[16];
    const float4* h4 = reinterpret_cast<const float4*>(h + (size_t)n * F);
#pragma unroll
    for (int i = 0; i < 16; i++) hv[i] = h4[i];

    double u = 0.0, v = 0.0;
    float4 tq;
    float4* trow = reinterpret_cast<float4*>(tfeat + (size_t)n * F);
#pragma unroll 4
    for (int j = 0; j < F; j++) {
        const float4* row = reinterpret_cast<const float4*>(&sWT[j * F]);
        float t = 0.f;
#pragma unroll
        for (int kk = 0; kk < 16; kk++) {
            float4 w = row[kk];
            float4 x = hv[kk];
            t = fmaf(x.x, w.x, t);
            t = fmaf(x.y, w.y, t);
            t = fmaf(x.z, w.z, t);
            t = fmaf(x.w, w.w, t);
        }
        t = t + sb[j];
        u = fma((double)t, swfA[j], u);
        v = fma((double)t, swfB[j], v);
        if ((j & 3) == 0) tq.x = t;
        else if ((j & 3) == 1) tq.y = t;
        else if ((j & 3) == 2) tq.z = t;
        else { tq.w = t; trow[j >> 2] = tq; }
    }
    u_arr[n] = (float)u;
    v_arr[n] = (float)v;
}

// ---------------------------------------------------------------------------
// Tier-2 sign fallback: literal fp32 192-term sequential FMA in the
// reference's e_feat section order (rare: |fp32 margin| < 1e-4).
// ---------------------------------------------------------------------------
__device__ __noinline__ float tier2_sign(
    const float* __restrict__ tfeat, const float* __restrict__ sWf,
    int s, int d, float bf)
{
    const float4* ts = reinterpret_cast<const float4*>(tfeat + (size_t)s * F);
    const float4* td = reinterpret_cast<const float4*>(tfeat + (size_t)d * F);
    float sv[F];
#pragma unroll
    for (int i = 0; i < 16; i++) {
        float4 a = ts[i];
        sv[4 * i + 0] = a.x; sv[4 * i + 1] = a.y;
        sv[4 * i + 2] = a.z; sv[4 * i + 3] = a.w;
    }
    float acc = 0.f;
#pragma unroll
    for (int j = 0; j < F; j++) acc = fmaf(sv[j], sWf[j], acc);
#pragma unroll
    for (int i = 0; i < 16; i++) {
        float4 a = td[i];
        acc = fmaf(a.x, sWf[F + 4 * i + 0], acc);
        acc = fmaf(a.y, sWf[F + 4 * i + 1], acc);
        acc = fmaf(a.z, sWf[F + 4 * i + 2], acc);
        acc = fmaf(a.w, sWf[F + 4 * i + 3], acc);
    }
#pragma unroll
    for (int i = 0; i < 16; i++) {
        float4 a = td[i];
        acc = fmaf(sv[4 * i + 0] - a.x, sWf[2 * F + 4 * i + 0], acc);
        acc = fmaf(sv[4 * i + 1] - a.y, sWf[2 * F + 4 * i + 1], acc);
        acc = fmaf(sv[4 * i + 2] - a.z, sWf[2 * F + 4 * i + 2], acc);
        acc = fmaf(sv[4 * i + 3] - a.w, sWf[2 * F + 4 * i + 3], acc);
    }
    float sp = acc + bf;
    return (sp > 0.f) ? 1.f : (sp < 0.f ? -1.f : 0.f);
}

// ---------------------------------------------------------------------------
// K2 fused: blocks [0,nbw): node W_w path. blocks [nbw,..): edge path —
// XCD-sharded count (L2-local workgroup-scope atomic) + sign + slot scatter.
// All writers of shard x run on XCD x (physical xcc_id read) -> no cross-XCD
// line sharing; kernel-end writeback publishes to K3.
// ---------------------------------------------------------------------------
__global__ __launch_bounds__(256) void ww_count_scatter_kernel(
    const float* __restrict__ h,
    const float* __restrict__ W_w, const float* __restrict__ b_w,
    const float* __restrict__ W_a,
    __half* __restrict__ hp,
    float* __restrict__ a_src, float* __restrict__ a_dst,
    const int* __restrict__ src_idx, const int* __restrict__ dst_idx,
    const float* __restrict__ u_arr, const float* __restrict__ v_arr,
    const float* __restrict__ tfeat, const float* __restrict__ W_f,
    const float* __restrict__ b_f,
    unsigned* __restrict__ cnt, unsigned* __restrict__ slot,
    unsigned* __restrict__ of_list, unsigned* __restrict__ of_cnt,
    int N, int E, int nbw, unsigned of_cap)
{
    __shared__ float sWT[F * F];   // W_w blocks: weights; edge blocks: sWf[0,192)
    __shared__ float sb[F];
    __shared__ float sWa[32];

    int tid = threadIdx.x;

    if (blockIdx.x < nbw) {
        // ---- node W_w path ----
        for (int i = tid; i < F * F; i += 256) {
            int k = i >> 6, j = i & 63;
            sWT[j * F + k] = W_w[i];
        }
        if (tid < F) sb[tid] = b_w[tid];
        if (tid < 32) sWa[tid] = W_a[tid];
        __syncthreads();

        int n = blockIdx.x * 256 + tid;
        if (n >= N) return;

        float4 hv[16];
        const float4* h4 = reinterpret_cast<const float4*>(h + (size_t)n * F);
#pragma unroll
        for (int i = 0; i < 16; i++) hv[i] = h4[i];

        __half2* prow = reinterpret_cast<__half2*>(hp + (size_t)n * F);
#pragma unroll
        for (int qh = 0; qh < 4; qh++) {
            float asq = 0.f, adq = 0.f;
            float pprev = 0.f;
#pragma unroll 4
            for (int jj = 0; jj < 16; jj++) {
                int j = qh * 16 + jj;
                const float4* row = reinterpret_cast<const float4*>(&sWT[j * F]);
                float p = 0.f;
#pragma unroll
                for (int kk = 0; kk < 16; kk++) {
                    float4 w = row[kk];
                    float4 x = hv[kk];
                    p = fmaf(x.x, w.x, p);
                    p = fmaf(x.y, w.y, p);
                    p = fmaf(x.z, w.z, p);
                    p = fmaf(x.w, w.w, p);
                }
                p = p + sb[j];
                asq = fmaf(p, sWa[jj], asq);
                adq = fmaf(p, sWa[16 + jj], adq);
                if ((jj & 1) == 0) pprev = p;
                else prow[j >> 1] = __floats2half2_rn(pprev, p);
            }
            a_src[n * HEADS + qh] = asq;
            a_dst[n * HEADS + qh] = adq;
        }
        return;
    }

    // ---- edge path ----
    float* sWf = sWT;   // reuse first 192 floats
    if (tid < 3 * F) sWf[tid] = W_f[tid];
    __syncthreads();

    unsigned xcc;
    asm volatile("s_getreg_b32 %0, hwreg(HW_REG_XCC_ID)" : "=s"(xcc));
    xcc &= (SHARDS - 1);

    float bf = b_f[0];
    int eb = blockIdx.x - nbw;
    int e0 = eb * 512 + tid;
    int e1 = e0 + 256;
    bool ok0 = e0 < E, ok1 = e1 < E;

    int s0 = 0, d0 = 0, s1 = 0, d1 = 0;
    if (ok0) { s0 = src_idx[e0]; d0 = dst_idx[e0]; }
    if (ok1) { s1 = src_idx[e1]; d1 = dst_idx[e1]; }

    // independent long-latency ops issued up front
    float us0 = ok0 ? u_arr[s0] : 0.f, vd0 = ok0 ? v_arr[d0] : 0.f;
    float us1 = ok1 ? u_arr[s1] : 0.f, vd1 = ok1 ? v_arr[d1] : 0.f;
    unsigned p0 = ok0 ? __hip_atomic_fetch_add(&cnt[(size_t)xcc * N + d0], 1u,
                          __ATOMIC_RELAXED, __HIP_MEMORY_SCOPE_WORKGROUP) : 0u;
    unsigned p1 = ok1 ? __hip_atomic_fetch_add(&cnt[(size_t)xcc * N + d1], 1u,
                          __ATOMIC_RELAXED, __HIP_MEMORY_SCOPE_WORKGROUP) : 0u;

    float m0 = us0 + vd0 + bf;
    float m1 = us1 + vd1 + bf;

    float sg0 = (fabsf(m0) >= 1e-4f) ? ((m0 > 0.f) ? 1.f : -1.f)
                                     : (ok0 ? tier2_sign(tfeat, sWf, s0, d0, bf) : 0.f);
    float sg1 = (fabsf(m1) >= 1e-4f) ? ((m1 > 0.f) ? 1.f : -1.f)
                                     : (ok1 ? tier2_sign(tfeat, sWf, s1, d1, bf) : 0.f);

    if (ok0) {
        unsigned c0 = (sg0 > 0.f) ? 0u : (sg0 < 0.f ? 1u : 2u);
        unsigned val = (unsigned)s0 | (c0 << 30);
        if (p0 < (unsigned)CAPS) slot[((size_t)xcc * N + d0) * CAPS + p0] = val;
        else {
            unsigned oi = atomicAdd(of_cnt, 1u);
            if (oi < of_cap) { of_list[2 * oi] = (unsigned)d0; of_list[2 * oi + 1] = val; }
        }
    }
    if (ok1) {
        unsigned c1 = (sg1 > 0.f) ? 0u : (sg1 < 0.f ? 1u : 2u);
        unsigned val = (unsigned)s1 | (c1 << 30);
        if (p1 < (unsigned)CAPS) slot[((size_t)xcc * N + d1) * CAPS + p1] = val;
        else {
            unsigned oi = atomicAdd(of_cnt, 1u);
            if (oi < of_cap) { of_list[2 * oi] = (unsigned)d1; of_list[2 * oi + 1] = val; }
        }
    }
}

// ---------------------------------------------------------------------------
// K3: one wave per dst. Read 8 shard counts (broadcast), prefix-map lanes to
// (shard,pos); Phase A: one slot per lane -> 4 signed weights in LDS + esum;
// butterfly. Phase B: 8-way ILP LDS-fed fp16 hp gather; one store.
// Slow path (deg>64 or shard overflow — never for this graph): global
// recompute over clamped slots + of_list.
// ---------------------------------------------------------------------------
__global__ __launch_bounds__(256) void dst_gather_kernel(
    const unsigned* __restrict__ cnt,
    const unsigned* __restrict__ slot,
    const unsigned* __restrict__ of_list, const unsigned* __restrict__ of_cnt,
    const float* __restrict__ a_src, const float* __restrict__ a_dst,
    const float* __restrict__ b_a,
    const __half* __restrict__ hp,
    float* __restrict__ out, int N)
{
    __shared__ float sw[4][MAXDEG * 4];     // [wave][slot*4+head] = sgn*ex
    __shared__ unsigned ssrc[4][MAXDEG];    // [wave][slot] = src index

    int tid = threadIdx.x;
    int wslot = tid >> 6;
    int lane = tid & 63;
    int q = lane >> 4;
    int d = (blockIdx.x * 256 + tid) >> 6;
    bool valid = d < N;

    float ba = b_a[0];
    float4 ad4 = make_float4(0.f, 0.f, 0.f, 0.f);
    unsigned csh[SHARDS], pre[SHARDS];
    unsigned deg = 0;
    bool ofl = false;
    if (valid) {
        ad4 = *reinterpret_cast<const float4*>(a_dst + (size_t)d * HEADS);
#pragma unroll
        for (int x = 0; x < SHARDS; x++) {
            unsigned c = cnt[(size_t)x * N + d];
            csh[x] = c; pre[x] = deg; deg += c;
            if (c > (unsigned)CAPS) ofl = true;
        }
    }
    float adq = (q == 0) ? ad4.x : (q == 1) ? ad4.y : (q == 2) ? ad4.z : ad4.w;
    bool fast = valid && (deg <= (unsigned)MAXDEG) && !ofl;

    // Phase A
    float4 p = make_float4(0.f, 0.f, 0.f, 0.f);
    if (fast && lane < (int)deg) {
        int shard = 0; unsigned pos = 0;
#pragma unroll
        for (int x = 0; x < SHARDS; x++)
            if ((unsigned)lane >= pre[x] && (unsigned)lane < pre[x] + csh[x]) {
                shard = x; pos = (unsigned)lane - pre[x];
            }
        unsigned sp = slot[((size_t)shard * N + d) * CAPS + pos];
        unsigned s = sp & 0x3FFFFFFFu;
        unsigned c = sp >> 30;
        float sgn = (c == 0u) ? 1.f : (c == 1u ? -1.f : 0.f);
        float4 as4 = *reinterpret_cast<const float4*>(a_src + (size_t)s * HEADS);
        float ap0 = fmaf(sgn, as4.x, ad4.x) + ba;
        float ap1 = fmaf(sgn, as4.y, ad4.y) + ba;
        float ap2 = fmaf(sgn, as4.z, ad4.z) + ba;
        float ap3 = fmaf(sgn, as4.w, ad4.w) + ba;
        float e0 = expf(ap0 > 0.f ? ap0 : 0.01f * ap0);
        float e1 = expf(ap1 > 0.f ? ap1 : 0.01f * ap1);
        float e2 = expf(ap2 > 0.f ? ap2 : 0.01f * ap2);
        float e3 = expf(ap3 > 0.f ? ap3 : 0.01f * ap3);
        p = make_float4(e0, e1, e2, e3);
        *reinterpret_cast<float4*>(&sw[wslot][lane * 4]) =
            make_float4(sgn * e0, sgn * e1, sgn * e2, sgn * e3);
        ssrc[wslot][lane] = s;
    }
    if (valid && !fast) {
        // slow path esum: clamped slots + overflow list
        for (int x = 0; x < SHARDS; x++) {
            unsigned cc = min(csh[x], (unsigned)CAPS);
            for (unsigned i = lane; i < cc; i += 64) {
                unsigned sp = slot[((size_t)x * N + d) * CAPS + i];
                unsigned s = sp & 0x3FFFFFFFu;
                unsigned c = sp >> 30;
                float sgn = (c == 0u) ? 1.f : (c == 1u ? -1.f : 0.f);
                float4 as4 = *reinterpret_cast<const float4*>(a_src + (size_t)s * HEADS);
                float ap0 = fmaf(sgn, as4.x, ad4.x) + ba;
                float ap1 = fmaf(sgn, as4.y, ad4.y) + ba;
                float ap2 = fmaf(sgn, as4.z, ad4.z) + ba;
                float ap3 = fmaf(sgn, as4.w, ad4.w) + ba;
                p.x += expf(ap0 > 0.f ? ap0 : 0.01f * ap0);
                p.y += expf(ap1 > 0.f ? ap1 : 0.01f * ap1);
                p.z += expf(ap2 > 0.f ? ap2 : 0.01f * ap2);
                p.w += expf(ap3 > 0.f ? ap3 : 0.01f * ap3);
            }
        }
        unsigned on = *of_cnt;
        for (unsigned i = lane; i < on; i += 64) {
            if (of_list[2 * i] == (unsigned)d) {
                unsigned sp = of_list[2 * i + 1];
                unsigned s = sp & 0x3FFFFFFFu;
                unsigned c = sp >> 30;
                float sgn = (c == 0u) ? 1.f : (c == 1u ? -1.f : 0.f);
                float4 as4 = *reinterpret_cast<const float4*>(a_src + (size_t)s * HEADS);
                float ap0 = fmaf(sgn, as4.x, ad4.x) + ba;
                float ap1 = fmaf(sgn, as4.y, ad4.y) + ba;
                float ap2 = fmaf(sgn, as4.z, ad4.z) + ba;
                float ap3 = fmaf(sgn, as4.w, ad4.w) + ba;
                p.x += expf(ap0 > 0.f ? ap0 : 0.01f * ap0);
                p.y += expf(ap1 > 0.f ? ap1 : 0.01f * ap1);
                p.z += expf(ap2 > 0.f ? ap2 : 0.01f * ap2);
                p.w += expf(ap3 > 0.f ? ap3 : 0.01f * ap3);
            }
        }
    }
    __syncthreads();

#pragma unroll
    for (int off = 32; off >= 1; off >>= 1) {
        p.x += __shfl_xor(p.x, off);
        p.y += __shfl_xor(p.y, off);
        p.z += __shfl_xor(p.z, off);
        p.w += __shfl_xor(p.w, off);
    }
    if (!valid) return;

    float esq = (q == 0) ? p.x : (q == 1) ? p.y : (q == 2) ? p.z : p.w;
    float rinv = (deg > 0) ? (1.0f / esq) : 0.f;

    float a0 = 0.f, a1 = 0.f, a2 = 0.f, a3 = 0.f;
    if (fast) {
        const float* swb = &sw[wslot][0];
        const unsigned* ssb = &ssrc[wslot][0];
        unsigned t0 = 0;
        for (; t0 + 8 <= deg; t0 += 8) {
            float w0 = swb[(t0 + 0) * 4 + q], w1 = swb[(t0 + 1) * 4 + q];
            float w2 = swb[(t0 + 2) * 4 + q], w3 = swb[(t0 + 3) * 4 + q];
            float w4 = swb[(t0 + 4) * 4 + q], w5 = swb[(t0 + 5) * 4 + q];
            float w6 = swb[(t0 + 6) * 4 + q], w7 = swb[(t0 + 7) * 4 + q];
            unsigned s0 = ssb[t0 + 0], s1 = ssb[t0 + 1];
            unsigned s2 = ssb[t0 + 2], s3 = ssb[t0 + 3];
            unsigned s4 = ssb[t0 + 4], s5 = ssb[t0 + 5];
            unsigned s6 = ssb[t0 + 6], s7 = ssb[t0 + 7];
            float h0 = __half2float(hp[((size_t)s0 << 6) | (unsigned)lane]);
            float h1 = __half2float(hp[((size_t)s1 << 6) | (unsigned)lane]);
            float h2 = __half2float(hp[((size_t)s2 << 6) | (unsigned)lane]);
            float h3 = __half2float(hp[((size_t)s3 << 6) | (unsigned)lane]);
            float h4 = __half2float(hp[((size_t)s4 << 6) | (unsigned)lane]);
            float h5 = __half2float(hp[((size_t)s5 << 6) | (unsigned)lane]);
            float h6 = __half2float(hp[((size_t)s6 << 6) | (unsigned)lane]);
            float h7 = __half2float(hp[((size_t)s7 << 6) | (unsigned)lane]);
            a0 = fmaf(w0, h0, a0); a1 = fmaf(w1, h1, a1);
            a2 = fmaf(w2, h2, a2); a3 = fmaf(w3, h3, a3);
            a0 = fmaf(w4, h4, a0); a1 = fmaf(w5, h5, a1);
            a2 = fmaf(w6, h6, a2); a3 = fmaf(w7, h7, a3);
        }
        for (; t0 < deg; t0++) {
            float w = swb[t0 * 4 + q];
            unsigned s = ssb[t0];
            a0 = fmaf(w, __half2float(hp[((size_t)s << 6) | (unsigned)lane]), a0);
        }
    } else {
        // slow path: serial recompute over clamped slots + of_list
        for (int x = 0; x < SHARDS; x++) {
            unsigned cc = min(csh[x], (unsigned)CAPS);
            for (unsigned i = 0; i < cc; i++) {
                unsigned sp = slot[((size_t)x * N + d) * CAPS + i];
                unsigned s = sp & 0x3FFFFFFFu;
                unsigned c = sp >> 30;
                float g = (c == 0u) ? 1.f : (c == 1u ? -1.f : 0.f);
                float asv = a_src[s * HEADS + q];
                float ap = fmaf(g, asv, adq) + ba;
                float ev = expf(ap > 0.f ? ap : 0.01f * ap);
                a0 = fmaf(ev * g, __half2float(hp[((size_t)s << 6) | (unsigned)lane]), a0);
            }
        }
        unsigned on = *of_cnt;
        for (unsigned i = 0; i < on; i++) {
            if (of_list[2 * i] == (unsigned)d) {
                unsigned sp = of_list[2 * i + 1];
                unsigned s = sp & 0x3FFFFFFFu;
                unsigned c = sp >> 30;
                float g = (c == 0u) ? 1.f : (c == 1u ? -1.f : 0.f);
                float asv = a_src[s * HEADS + q];
                float ap = fmaf(g, asv, adq) + ba;
                float ev = expf(ap > 0.f ? ap : 0.01f * ap);
                a0 = fmaf(ev * g, __half2float(hp[((size_t)s << 6) | (unsigned)lane]), a0);
            }
        }
    }
    out[((size_t)d << 6) | (unsigned)lane] = ((a0 + a1) + (a2 + a3)) * rinv;
}

// ---------------------------------------------------------------------------
extern "C" void kernel_launch(void* const* d_in, const int* in_sizes, int n_in,
                              void* d_out, int out_size, void* d_ws, size_t ws_size,
                              hipStream_t stream)
{
    const float* h       = (const float*)d_in[0];
    const int*   src_idx = (const int*)d_in[1];
    const int*   dst_idx = (const int*)d_in[2];
    const float* W_w     = (const float*)d_in[3];
    const float* b_w     = (const float*)d_in[4];
    const float* W_a     = (const float*)d_in[5];
    const float* b_a     = (const float*)d_in[6];
    const float* W_d     = (const float*)d_in[7];
    const float* b_d     = (const float*)d_in[8];
    const float* W_f     = (const float*)d_in[9];
    const float* b_f     = (const float*)d_in[10];

    int N = in_sizes[0] / F;
    int E = in_sizes[1];
    int nb = (N + 255) / 256;
    int neb = (E + 511) / 512;
    unsigned of_cap = (unsigned)(E / 8);

    char* ws = (char*)d_ws;
    float*    tfeat  = (float*)ws;     ws += (size_t)N * F * 4;              // 12.8MB
    __half*   hp     = (__half*)ws;    ws += (size_t)N * F * 2;              // 6.4MB
    float*    u_arr  = (float*)ws;     ws += (size_t)N * 4;                  // 0.2MB
    float*    v_arr  = (float*)ws;     ws += (size_t)N * 4;                  // 0.2MB
    float*    a_src  = (float*)ws;     ws += (size_t)N * HEADS * 4;          // 0.8MB
    float*    a_dst  = (float*)ws;     ws += (size_t)N * HEADS * 4;          // 0.8MB
    unsigned* cnt    = (unsigned*)ws;  ws += (size_t)SHARDS * N * 4;         // 1.6MB
    unsigned* of_cnt = (unsigned*)ws;  ws += 64;                             // 64B
    unsigned* slot   = (unsigned*)ws;  ws += (size_t)SHARDS * N * CAPS * 4;  // 25.6MB
    unsigned* of_list= (unsigned*)ws;  ws += (size_t)of_cap * 8;             // 1MB

    float* out = (float*)d_out;

    node_wd_kernel<<<nb, 256, 0, stream>>>(
        h, W_d, b_d, W_f, tfeat, u_arr, v_arr, cnt, of_cnt, N);

    ww_count_scatter_kernel<<<nb + neb, 256, 0, stream>>>(
        h, W_w, b_w, W_a, hp, a_src, a_dst,
        src_idx, dst_idx, u_arr, v_arr, tfeat, W_f, b_f,
        cnt, slot, of_list, of_cnt, N, E, nb, of_cap);

    dst_gather_kernel<<<(N * 64 + 255) / 256, 256, 0, stream>>>(
        cnt, slot, of_list, of_cnt, a_src, a_dst, b_a, hp, out, N);
}